// Round 8
// baseline (391.295 us; speedup 1.0000x reference)
//
#include <hip/hip_runtime.h>
#include <stdint.h>

#define HW    50176   // 224*224
#define BATCH 16
#define NSEG  196
#define EMB   16
#define MC    16
#define JITTER 0.001f
#define EBLK  14      // emb blocks per batch
#define PXB   3584    // pixels per emb block (50176/14)

typedef float vfloat4 __attribute__((ext_vector_type(4)));  // native vec for nontemporal builtins

// ---------------- threefry2x32 (20 rounds), bit-exact vs JAX ----------------
__host__ __device__ inline void threefry2x32(uint32_t k0, uint32_t k1,
                                             uint32_t x0, uint32_t x1,
                                             uint32_t& o0, uint32_t& o1) {
  uint32_t k2 = k0 ^ k1 ^ 0x1BD11BDAu;
#define TFR(r) { x0 += x1; x1 = (x1 << (r)) | (x1 >> (32 - (r))); x1 ^= x0; }
  x0 += k0; x1 += k1;
  TFR(13) TFR(15) TFR(26) TFR(6)
  x0 += k1; x1 += k2 + 1u;
  TFR(17) TFR(29) TFR(16) TFR(24)
  x0 += k2; x1 += k0 + 2u;
  TFR(13) TFR(15) TFR(26) TFR(6)
  x0 += k0; x1 += k1 + 3u;
  TFR(17) TFR(29) TFR(16) TFR(24)
  x0 += k1; x1 += k2 + 4u;
  TFR(13) TFR(15) TFR(26) TFR(6)
  x0 += k2; x1 += k0 + 5u;
#undef TFR
  o0 = x0; o1 = x1;
}

// XLA ErfInv (f32), Giles polynomial
__device__ inline float erfinv_f32(float x) {
  float w = -log1pf(-x * x);
  float p;
  if (w < 5.0f) {
    w = w - 2.5f;
    p = 2.81022636e-08f;
    p = 3.43273939e-07f + p * w;
    p = -3.5233877e-06f + p * w;
    p = -4.39150654e-06f + p * w;
    p = 0.00021858087f + p * w;
    p = -0.00125372503f + p * w;
    p = -0.00417768164f + p * w;
    p = 0.246640727f + p * w;
    p = 1.50140941f + p * w;
  } else {
    w = sqrtf(w) - 3.0f;
    p = -0.000200214257f;
    p = 0.000100950558f + p * w;
    p = 0.00134934322f + p * w;
    p = -0.00367342844f + p * w;
    p = 0.00573950773f + p * w;
    p = -0.0076224613f + p * w;
    p = 0.00943887047f + p * w;
    p = 1.00167406f + p * w;
    p = 2.83297682f + p * w;
  }
  return p * x;
}

__device__ inline float bits_to_f01(uint32_t bits) {
  uint32_t fb = (bits >> 9) | 0x3F800000u;
  return __uint_as_float(fb) - 1.0f;
}

// wave-uniform broadcast via v_readlane (bit-identical to __shfl for uniform
// lane index with all lanes active; lands in SGPR — no DS op, no VGPR cost)
__device__ inline float readlane_f(float v, int lane) {
  return __int_as_float(__builtin_amdgcn_readlane(__float_as_int(v), lane));
}

// ---------------- K1: emb + pixel_probs + per-block partial sums -----------
// partial layout: [b*EBLK+bb][17][196]  (j-major, g coalesced)
__global__ __launch_bounds__(256) void emb_kernel(
    const float* __restrict__ x, const int* __restrict__ groups,
    const float* __restrict__ Wc, const float* __restrict__ bc,
    float* __restrict__ partial, float* __restrict__ pixel_probs) {
  __shared__ float lsum[NSEG * 17];
  int b = blockIdx.x / EBLK;
  int blk = blockIdx.x % EBLK;
  int tid = threadIdx.x;
  for (int i = tid; i < NSEG * 17; i += 256) lsum[i] = 0.0f;
  __syncthreads();
  const float* xb = x + (size_t)b * 3 * HW;
  for (int k = 0; k < PXB / 256; ++k) {
    int p = blk * PXB + k * 256 + tid;
    float x0 = xb[p], x1 = xb[HW + p], x2 = xb[2 * HW + p];
    int g = groups[b * HW + p];
    float* dst = lsum + g * 17;
#pragma unroll
    for (int j = 0; j < EMB; ++j) {
      float e = Wc[j * 3 + 0] * x0 + Wc[j * 3 + 1] * x1;
      e = e + Wc[j * 3 + 2] * x2 + bc[j];
      if (j == 0) pixel_probs[b * HW + p] = 1.0f / (1.0f + expf(-e));
      atomicAdd(&dst[j], e);
    }
    atomicAdd(&dst[16], 1.0f);
  }
  __syncthreads();
  // transposed coalesced flush (no global atomics)
  float* pb = partial + (size_t)blockIdx.x * (17 * NSEG);
  if (tid < NSEG) {
#pragma unroll
    for (int j = 0; j < 17; ++j) pb[j * NSEG + tid] = lsum[tid * 17 + j];
  }
}

// ---------------- K2: stats — mu, group_probs, G (column-major) ------------
__global__ __launch_bounds__(256) void stats_kernel(
    const float* __restrict__ partial, float* __restrict__ mu_ws,
    float* __restrict__ group_probs, float* __restrict__ Gc /* [B][15][196] */) {
  int b = blockIdx.x;
  int i = threadIdx.x;
  if (i >= NSEG) return;
  float acc[17];
#pragma unroll
  for (int j = 0; j < 17; ++j) acc[j] = 0.0f;
  for (int bb = 0; bb < EBLK; ++bb) {
    const float* pb = partial + (size_t)(b * EBLK + bb) * (17 * NSEG);
#pragma unroll
    for (int j = 0; j < 17; ++j) acc[j] += pb[j * NSEG + i];
  }
  float denom = fmaxf(acc[16], 1.0f);
  float m = acc[0] / denom;
  mu_ws[b * NSEG + i] = m;
  group_probs[b * NSEG + i] = 1.0f / (1.0f + expf(-m));
#pragma unroll
  for (int j = 0; j < 15; ++j)
    Gc[((size_t)b * 15 + j) * NSEG + i] = acc[j + 1] / denom;
}

// ---------------- K3: sigma = G G^T + jitter*I (tiled) ---------------------
__global__ __launch_bounds__(256) void sigma_kernel(
    const float* __restrict__ Gc, float* __restrict__ sigma_out) {
  int b = blockIdx.x / 7;
  int tile = blockIdx.x % 7;
  int tid = threadIdx.x;
  __shared__ float ge[15][NSEG];
  if (tid < NSEG) {
#pragma unroll
    for (int j = 0; j < 15; ++j) ge[j][tid] = Gc[((size_t)b * 15 + j) * NSEG + tid];
  }
  __syncthreads();
  if (tid >= NSEG) return;
  int t = tid;
  for (int r = 0; r < 28; ++r) {
    int s = tile * 28 + r;
    float acc = 0.0f;
#pragma unroll
    for (int j = 0; j < 15; ++j) acc = fmaf(ge[j][s], ge[j][t], acc);
    if (s == t) acc += JITTER;
    sigma_out[((size_t)b * NSEG + s) * NSEG + t] = acc;
  }
}

// ---------------- K4: fused rng + low-rank Cholesky + L@eps + hard ---------
// sigma = jitter*I + G G^T.  Schur invariant keeps only G (rank 15) as state:
//   d = sqrt(j + |g_k|^2); L[i,k] = g_i.g_k/d; g_i -= beta (g_i.g_k) g_k,
//   beta = 1/(d(d+sqrt(j))).
// 4 waves/block, each wave replicates the recurrence and owns a 4-wide MC
// slice.  Row-k broadcast via v_readlane (wave-uniform lane index) into
// SGPRs — replaces round-5's 15 serialized ds_bpermutes (~1600 cyc/step
// under VGPR starvation) with ~15 VALU ops; values bit-identical to the
// round-5 kernel that passed.  Rows retire: slot s is dead for k>=64(s+1).
// Slots must use COMPILE-TIME indices (round-3 scratch regression).
__global__ __launch_bounds__(256, 1) void cholmc_kernel(
    const float* __restrict__ Gc, const float* __restrict__ mu,
    uint32_t kg0, uint32_t kg1, uint32_t ku0, uint32_t ku1,
    float* __restrict__ hard) {
  int b = blockIdx.x;
  int tid = threadIdx.x;
  int lane = tid & 63;
  int wave = tid >> 6;
  __shared__ float eps_lds[NSEG * MC];  // 12.25 KB

  // prologue: eps = sqrt(2)*erfinv(bits) straight into LDS
  for (int t = tid; t < NSEG * MC; t += 256) {
    uint32_t a0, a1;
    threefry2x32(kg0, kg1, 0u, (uint32_t)(b * NSEG * MC + t), a0, a1);
    float f = bits_to_f01(a0 ^ a1);
    const float lo = -0.99999994f;  // nextafter(-1,0)
    float u = fmaxf(lo, f * (1.0f - lo) + lo);
    eps_lds[t] = 1.4142135623730951f * erfinv_f32(u);
  }

  float g[4][15];
  float acc[4][4];
#pragma unroll
  for (int s = 0; s < 4; ++s) {
    int i = s * 64 + lane;
#pragma unroll
    for (int j = 0; j < 15; ++j)
      g[s][j] = (i < NSEG) ? Gc[((size_t)b * 15 + j) * NSEG + i] : 0.0f;
#pragma unroll
    for (int q = 0; q < 4; ++q) acc[s][q] = 0.0f;
  }
  __syncthreads();

  const float sj = 0.031622776601683794f;  // sqrt(jitter)
  for (int k = 0; k < NSEG; ++k) {
    int owner = k & 63;
    int s0 = k >> 6;  // wave-uniform; slots < s0 retired
    float gk[15];
    switch (s0) {  // compile-time register indices; uniform branch
      case 0:
#pragma unroll
        for (int j = 0; j < 15; ++j) gk[j] = readlane_f(g[0][j], owner);
        break;
      case 1:
#pragma unroll
        for (int j = 0; j < 15; ++j) gk[j] = readlane_f(g[1][j], owner);
        break;
      case 2:
#pragma unroll
        for (int j = 0; j < 15; ++j) gk[j] = readlane_f(g[2][j], owner);
        break;
      default:
#pragma unroll
        for (int j = 0; j < 15; ++j) gk[j] = readlane_f(g[3][j], owner);
        break;
    }
    float nrm = 0.0f;
#pragma unroll
    for (int j = 0; j < 15; ++j) nrm = fmaf(gk[j], gk[j], nrm);
    float dd = sqrtf(JITTER + nrm);
    float invd = 1.0f / dd;                // precise IEEE divide
    float beta = 1.0f / (dd * (dd + sj));  // stable Schur downdate scale
    const float4 ekv = *(const float4*)(eps_lds + k * MC + wave * 4);
    float ek[4] = {ekv.x, ekv.y, ekv.z, ekv.w};
#pragma unroll
    for (int s = 0; s < 4; ++s) {      // compile-time s; retirement guard inside
      if (s >= s0) {                   // wave-uniform branch
        int i = s * 64 + lane;
        float dot = 0.0f;
#pragma unroll
        for (int j = 0; j < 15; ++j) dot = fmaf(g[s][j], gk[j], dot);
        float lik = (i == k) ? dd : dot * invd;
        float w = (i >= k && i < NSEG) ? lik : 0.0f;
#pragma unroll
        for (int q = 0; q < 4; ++q) acc[s][q] = fmaf(w, ek[q], acc[s][q]);
        float bd = beta * dot;
#pragma unroll
        for (int j = 0; j < 15; ++j) g[s][j] = fmaf(-bd, gk[j], g[s][j]);
      }
    }
  }

  // epilogue: hard = (mu + L@eps + logistic) > 0, this wave's m-slice
#pragma unroll
  for (int s = 0; s < 4; ++s) {
    int i = s * 64 + lane;
    if (i < NSEG) {
      float mui = mu[b * NSEG + i];
      float4 outv;
      float* op = (float*)&outv;
#pragma unroll
      for (int q = 0; q < 4; ++q) {
        int m = wave * 4 + q;
        uint32_t a0, a1;
        threefry2x32(ku0, ku1, 0u, (uint32_t)(b * NSEG * MC + i * MC + m), a0, a1);
        float f = bits_to_f01(a0 ^ a1);
        const float mn = 1e-6f;
        const float mx = (float)(1.0 - 1e-6);
        float uu = fmaxf(mn, f * (mx - mn) + mn);
        float lg = logf(uu) - log1pf(-uu);
        float z = mui + acc[s][q] + lg;
        op[q] = (z > 0.0f) ? 1.0f : 0.0f;
      }
      *(float4*)(hard + ((size_t)b * NSEG + i) * MC + wave * 4) = outv;
    }
  }
}

// ---------------- K5: mask gather, one float4 per thread -------------------
__global__ __launch_bounds__(256) void mask_kernel(
    const int* __restrict__ groups, const float* __restrict__ hard,
    vfloat4* __restrict__ out) {
  int f = blockIdx.x * blockDim.x + threadIdx.x;  // float4 index
  if (f >= BATCH * 3 * HW * 4) return;
  int pix = f >> 2;          // (b*3+c)*HW + p
  int q = f & 3;
  int b = pix / (3 * HW);
  int p = pix % HW;
  int g = groups[b * HW + p];
  vfloat4 v = ((const vfloat4*)hard)[(b * NSEG + g) * 4 + q];
  __builtin_nontemporal_store(v, out + f);  // 154 MB never re-read: skip L2 alloc
}

extern "C" void kernel_launch(void* const* d_in, const int* in_sizes, int n_in,
                              void* d_out, int out_size, void* d_ws, size_t ws_size,
                              hipStream_t stream) {
  const float* x = (const float*)d_in[0];
  const int* groups = (const int*)d_in[1];
  const float* Wc = (const float*)d_in[2];
  const float* bc = (const float*)d_in[3];

  float* out = (float*)d_out;
  float* mask_out = out;                         // 38,535,168
  float* gp_out = out + 38535168;                //      3,136
  float* pp_out = gp_out + 3136;                 //    802,816
  float* sig_out = pp_out + 802816;              //    614,656

  float* ws = (float*)d_ws;
  float* partial = ws;                           // 224*3332 = 746,368
  float* mu_ws = ws + 746368;                    //   3,136
  float* Gc    = ws + 749504;                    //  47,040  (tot 3.19 MB)
  float* hard  = ws;                             // 50,176 — reuses dead partial

  emb_kernel<<<BATCH * EBLK, 256, 0, stream>>>(x, groups, Wc, bc, partial, pp_out);
  stats_kernel<<<BATCH, 256, 0, stream>>>(partial, mu_ws, gp_out, Gc);
  sigma_kernel<<<BATCH * 7, 256, 0, stream>>>(Gc, sig_out);

  uint32_t kg0, kg1, ku0, ku1;
  threefry2x32(0u, 42u, 0u, 0u, kg0, kg1);
  threefry2x32(0u, 42u, 0u, 1u, ku0, ku1);

  cholmc_kernel<<<BATCH, 256, 0, stream>>>(Gc, mu_ws, kg0, kg1, ku0, ku1, hard);
  mask_kernel<<<(BATCH * 3 * HW * 4 + 255) / 256, 256, 0, stream>>>(
      groups, hard, (vfloat4*)mask_out);
}

// Round 9
// 349.483 us; speedup vs baseline: 1.1196x; 1.1196x over previous
//
#include <hip/hip_runtime.h>
#include <stdint.h>

#define HW    50176   // 224*224
#define BATCH 16
#define NSEG  196
#define EMB   16
#define MC    16
#define JITTER 0.001f
#define EBLK  14      // emb blocks per batch
#define PXB   3584    // pixels per emb block (50176/14)

// ---------------- threefry2x32 (20 rounds), bit-exact vs JAX ----------------
__host__ __device__ inline void threefry2x32(uint32_t k0, uint32_t k1,
                                             uint32_t x0, uint32_t x1,
                                             uint32_t& o0, uint32_t& o1) {
  uint32_t k2 = k0 ^ k1 ^ 0x1BD11BDAu;
#define TFR(r) { x0 += x1; x1 = (x1 << (r)) | (x1 >> (32 - (r))); x1 ^= x0; }
  x0 += k0; x1 += k1;
  TFR(13) TFR(15) TFR(26) TFR(6)
  x0 += k1; x1 += k2 + 1u;
  TFR(17) TFR(29) TFR(16) TFR(24)
  x0 += k2; x1 += k0 + 2u;
  TFR(13) TFR(15) TFR(26) TFR(6)
  x0 += k0; x1 += k1 + 3u;
  TFR(17) TFR(29) TFR(16) TFR(24)
  x0 += k1; x1 += k2 + 4u;
  TFR(13) TFR(15) TFR(26) TFR(6)
  x0 += k2; x1 += k0 + 5u;
#undef TFR
  o0 = x0; o1 = x1;
}

// XLA ErfInv (f32), Giles polynomial
__device__ inline float erfinv_f32(float x) {
  float w = -log1pf(-x * x);
  float p;
  if (w < 5.0f) {
    w = w - 2.5f;
    p = 2.81022636e-08f;
    p = 3.43273939e-07f + p * w;
    p = -3.5233877e-06f + p * w;
    p = -4.39150654e-06f + p * w;
    p = 0.00021858087f + p * w;
    p = -0.00125372503f + p * w;
    p = -0.00417768164f + p * w;
    p = 0.246640727f + p * w;
    p = 1.50140941f + p * w;
  } else {
    w = sqrtf(w) - 3.0f;
    p = -0.000200214257f;
    p = 0.000100950558f + p * w;
    p = 0.00134934322f + p * w;
    p = -0.00367342844f + p * w;
    p = 0.00573950773f + p * w;
    p = -0.0076224613f + p * w;
    p = 0.00943887047f + p * w;
    p = 1.00167406f + p * w;
    p = 2.83297682f + p * w;
  }
  return p * x;
}

__device__ inline float bits_to_f01(uint32_t bits) {
  uint32_t fb = (bits >> 9) | 0x3F800000u;
  return __uint_as_float(fb) - 1.0f;
}

// wave-uniform broadcast via v_readlane (bit-identical to __shfl for uniform
// lane index with all lanes active; lands in SGPR)
__device__ inline float readlane_f(float v, int lane) {
  return __int_as_float(__builtin_amdgcn_readlane(__float_as_int(v), lane));
}

// ---------------- K1: emb + pixel_probs + per-block partial sums -----------
// partial layout: [b*EBLK+bb][17][196]  (j-major, g coalesced)
__global__ __launch_bounds__(256) void emb_kernel(
    const float* __restrict__ x, const int* __restrict__ groups,
    const float* __restrict__ Wc, const float* __restrict__ bc,
    float* __restrict__ partial, float* __restrict__ pixel_probs) {
  __shared__ float lsum[NSEG * 17];
  int b = blockIdx.x / EBLK;
  int blk = blockIdx.x % EBLK;
  int tid = threadIdx.x;
  for (int i = tid; i < NSEG * 17; i += 256) lsum[i] = 0.0f;
  __syncthreads();
  const float* xb = x + (size_t)b * 3 * HW;
  for (int k = 0; k < PXB / 256; ++k) {
    int p = blk * PXB + k * 256 + tid;
    float x0 = xb[p], x1 = xb[HW + p], x2 = xb[2 * HW + p];
    int g = groups[b * HW + p];
    float* dst = lsum + g * 17;
#pragma unroll
    for (int j = 0; j < EMB; ++j) {
      float e = Wc[j * 3 + 0] * x0 + Wc[j * 3 + 1] * x1;
      e = e + Wc[j * 3 + 2] * x2 + bc[j];
      if (j == 0) pixel_probs[b * HW + p] = 1.0f / (1.0f + expf(-e));
      atomicAdd(&dst[j], e);
    }
    atomicAdd(&dst[16], 1.0f);
  }
  __syncthreads();
  // transposed coalesced flush (no global atomics)
  float* pb = partial + (size_t)blockIdx.x * (17 * NSEG);
  if (tid < NSEG) {
#pragma unroll
    for (int j = 0; j < 17; ++j) pb[j * NSEG + tid] = lsum[tid * 17 + j];
  }
}

// ---------------- K2: stats — mu, group_probs, G (column-major) ------------
__global__ __launch_bounds__(256) void stats_kernel(
    const float* __restrict__ partial, float* __restrict__ mu_ws,
    float* __restrict__ group_probs, float* __restrict__ Gc /* [B][15][196] */) {
  int b = blockIdx.x;
  int i = threadIdx.x;
  if (i >= NSEG) return;
  float acc[17];
#pragma unroll
  for (int j = 0; j < 17; ++j) acc[j] = 0.0f;
  for (int bb = 0; bb < EBLK; ++bb) {
    const float* pb = partial + (size_t)(b * EBLK + bb) * (17 * NSEG);
#pragma unroll
    for (int j = 0; j < 17; ++j) acc[j] += pb[j * NSEG + i];
  }
  float denom = fmaxf(acc[16], 1.0f);
  float m = acc[0] / denom;
  mu_ws[b * NSEG + i] = m;
  group_probs[b * NSEG + i] = 1.0f / (1.0f + expf(-m));
#pragma unroll
  for (int j = 0; j < 15; ++j)
    Gc[((size_t)b * 15 + j) * NSEG + i] = acc[j + 1] / denom;
}

// ---------------- K3: sigma = G G^T + jitter*I (tiled) ---------------------
__global__ __launch_bounds__(256) void sigma_kernel(
    const float* __restrict__ Gc, float* __restrict__ sigma_out) {
  int b = blockIdx.x / 7;
  int tile = blockIdx.x % 7;
  int tid = threadIdx.x;
  __shared__ float ge[15][NSEG];
  if (tid < NSEG) {
#pragma unroll
    for (int j = 0; j < 15; ++j) ge[j][tid] = Gc[((size_t)b * 15 + j) * NSEG + tid];
  }
  __syncthreads();
  if (tid >= NSEG) return;
  int t = tid;
  for (int r = 0; r < 28; ++r) {
    int s = tile * 28 + r;
    float acc = 0.0f;
#pragma unroll
    for (int j = 0; j < 15; ++j) acc = fmaf(ge[j][s], ge[j][t], acc);
    if (s == t) acc += JITTER;
    sigma_out[((size_t)b * NSEG + s) * NSEG + t] = acc;
  }
}

// ---------------- K4: fused rng + low-rank Cholesky + L@eps + hard ---------
// sigma = jitter*I + G G^T.  Schur invariant keeps only G (rank 15) as state:
//   d = sqrt(j + |g_k|^2); L[i,k] = g_i.g_k/d; g_i -= beta (g_i.g_k) g_k,
//   beta = 1/(d(d+sqrt(j))).
// 4 waves/block, each wave replicates the recurrence and owns a 4-wide MC
// slice.  Row-k broadcast via v_readlane (wave-uniform lane index, SGPRs).
// The k-loop is split into FOUR PHASES with compile-time pivot slot and
// constant slot-loop bounds — round-8's per-iteration switch + runtime
// retirement guard produced ~390 VALU inst/step (measured via VALUBusy)
// vs ~155 needed; de-switching removes the multi-version body bloat.
// All FP ops identical in value and order to rounds 2/5/8 (passing):
// bit-identical output.  Slots use COMPILE-TIME indices only (round-3
// scratch regression).
__global__ __launch_bounds__(256, 1) void cholmc_kernel(
    const float* __restrict__ Gc, const float* __restrict__ mu,
    uint32_t kg0, uint32_t kg1, uint32_t ku0, uint32_t ku1,
    float* __restrict__ hard) {
  int b = blockIdx.x;
  int tid = threadIdx.x;
  int lane = tid & 63;
  int wave = tid >> 6;
  __shared__ float eps_lds[NSEG * MC];  // 12.25 KB

  // prologue: eps = sqrt(2)*erfinv(bits) straight into LDS
  for (int t = tid; t < NSEG * MC; t += 256) {
    uint32_t a0, a1;
    threefry2x32(kg0, kg1, 0u, (uint32_t)(b * NSEG * MC + t), a0, a1);
    float f = bits_to_f01(a0 ^ a1);
    const float lo = -0.99999994f;  // nextafter(-1,0)
    float u = fmaxf(lo, f * (1.0f - lo) + lo);
    eps_lds[t] = 1.4142135623730951f * erfinv_f32(u);
  }

  float g[4][15];
  float acc[4][4];
#pragma unroll
  for (int s = 0; s < 4; ++s) {
    int i = s * 64 + lane;
#pragma unroll
    for (int j = 0; j < 15; ++j)
      g[s][j] = (i < NSEG) ? Gc[((size_t)b * 15 + j) * NSEG + i] : 0.0f;
#pragma unroll
    for (int q = 0; q < 4; ++q) acc[s][q] = 0.0f;
  }
  __syncthreads();

  const float sj = 0.031622776601683794f;  // sqrt(jitter)

// One phase of the factorization: pivot slot P is a compile-time literal,
// slot loop has constant bounds (P..3).  ekv ds_read issued first so its
// latency hides under the readlane+norm chain.
#define CHOL_PHASE(P, KBEG, KEND)                                          \
  for (int k = (KBEG); k < (KEND); ++k) {                                  \
    const float4 ekv = *(const float4*)(eps_lds + k * MC + wave * 4);      \
    int owner = k & 63;                                                    \
    float gk[15];                                                          \
    _Pragma("unroll")                                                      \
    for (int j = 0; j < 15; ++j) gk[j] = readlane_f(g[P][j], owner);       \
    float nrm = 0.0f;                                                      \
    _Pragma("unroll")                                                      \
    for (int j = 0; j < 15; ++j) nrm = fmaf(gk[j], gk[j], nrm);            \
    float dd = sqrtf(JITTER + nrm);                                        \
    float invd = 1.0f / dd;                                                \
    float beta = 1.0f / (dd * (dd + sj));                                  \
    float ek[4] = {ekv.x, ekv.y, ekv.z, ekv.w};                            \
    _Pragma("unroll")                                                      \
    for (int s = (P); s < 4; ++s) {                                        \
      int i = s * 64 + lane;                                               \
      float dot = 0.0f;                                                    \
      _Pragma("unroll")                                                    \
      for (int j = 0; j < 15; ++j) dot = fmaf(g[s][j], gk[j], dot);        \
      float lik = (i == k) ? dd : dot * invd;                              \
      float w = (i >= k && i < NSEG) ? lik : 0.0f;                         \
      _Pragma("unroll")                                                    \
      for (int q = 0; q < 4; ++q) acc[s][q] = fmaf(w, ek[q], acc[s][q]);   \
      float bd = beta * dot;                                               \
      _Pragma("unroll")                                                    \
      for (int j = 0; j < 15; ++j) g[s][j] = fmaf(-bd, gk[j], g[s][j]);    \
    }                                                                      \
  }

  CHOL_PHASE(0, 0, 64)
  CHOL_PHASE(1, 64, 128)
  CHOL_PHASE(2, 128, 192)
  CHOL_PHASE(3, 192, 196)
#undef CHOL_PHASE

  // epilogue: hard = (mu + L@eps + logistic) > 0, this wave's m-slice
#pragma unroll
  for (int s = 0; s < 4; ++s) {
    int i = s * 64 + lane;
    if (i < NSEG) {
      float mui = mu[b * NSEG + i];
      float4 outv;
      float* op = (float*)&outv;
#pragma unroll
      for (int q = 0; q < 4; ++q) {
        int m = wave * 4 + q;
        uint32_t a0, a1;
        threefry2x32(ku0, ku1, 0u, (uint32_t)(b * NSEG * MC + i * MC + m), a0, a1);
        float f = bits_to_f01(a0 ^ a1);
        const float mn = 1e-6f;
        const float mx = (float)(1.0 - 1e-6);
        float uu = fmaxf(mn, f * (mx - mn) + mn);
        float lg = logf(uu) - log1pf(-uu);
        float z = mui + acc[s][q] + lg;
        op[q] = (z > 0.0f) ? 1.0f : 0.0f;
      }
      *(float4*)(hard + ((size_t)b * NSEG + i) * MC + wave * 4) = outv;
    }
  }
}

// ---------------- K5: mask gather, one float4 per thread -------------------
// Plain (cached) stores: round-5/8's nontemporal stores are a suspect for
// ~100 us of hidden write-path cost (MTYPE-NC bypass); this round measures
// the cached path.
__global__ __launch_bounds__(256) void mask_kernel(
    const int* __restrict__ groups, const float* __restrict__ hard,
    float4* __restrict__ out) {
  int f = blockIdx.x * blockDim.x + threadIdx.x;  // float4 index
  if (f >= BATCH * 3 * HW * 4) return;
  int pix = f >> 2;          // (b*3+c)*HW + p
  int q = f & 3;
  int b = pix / (3 * HW);
  int p = pix % HW;
  int g = groups[b * HW + p];
  out[f] = ((const float4*)hard)[(b * NSEG + g) * 4 + q];
}

extern "C" void kernel_launch(void* const* d_in, const int* in_sizes, int n_in,
                              void* d_out, int out_size, void* d_ws, size_t ws_size,
                              hipStream_t stream) {
  const float* x = (const float*)d_in[0];
  const int* groups = (const int*)d_in[1];
  const float* Wc = (const float*)d_in[2];
  const float* bc = (const float*)d_in[3];

  float* out = (float*)d_out;
  float* mask_out = out;                         // 38,535,168
  float* gp_out = out + 38535168;                //      3,136
  float* pp_out = gp_out + 3136;                 //    802,816
  float* sig_out = pp_out + 802816;              //    614,656

  float* ws = (float*)d_ws;
  float* partial = ws;                           // 224*3332 = 746,368
  float* mu_ws = ws + 746368;                    //   3,136
  float* Gc    = ws + 749504;                    //  47,040  (tot 3.19 MB)
  float* hard  = ws;                             // 50,176 — reuses dead partial

  emb_kernel<<<BATCH * EBLK, 256, 0, stream>>>(x, groups, Wc, bc, partial, pp_out);
  stats_kernel<<<BATCH, 256, 0, stream>>>(partial, mu_ws, gp_out, Gc);
  sigma_kernel<<<BATCH * 7, 256, 0, stream>>>(Gc, sig_out);

  uint32_t kg0, kg1, ku0, ku1;
  threefry2x32(0u, 42u, 0u, 0u, kg0, kg1);
  threefry2x32(0u, 42u, 0u, 1u, ku0, ku1);

  cholmc_kernel<<<BATCH, 256, 0, stream>>>(Gc, mu_ws, kg0, kg1, ku0, ku1, hard);
  mask_kernel<<<(BATCH * 3 * HW * 4 + 255) / 256, 256, 0, stream>>>(
      groups, hard, (float4*)mask_out);
}

// Round 10
// 349.367 us; speedup vs baseline: 1.1200x; 1.0003x over previous
//
#include <hip/hip_runtime.h>
#include <stdint.h>

#define HW    50176   // 224*224
#define BATCH 16
#define NSEG  196
#define EMB   16
#define MC    16
#define JITTER 0.001f
#define EBLK  14      // emb blocks per batch
#define PXB   3584    // pixels per emb block (50176/14)

// ---------------- threefry2x32 (20 rounds), bit-exact vs JAX ----------------
__host__ __device__ inline void threefry2x32(uint32_t k0, uint32_t k1,
                                             uint32_t x0, uint32_t x1,
                                             uint32_t& o0, uint32_t& o1) {
  uint32_t k2 = k0 ^ k1 ^ 0x1BD11BDAu;
#define TFR(r) { x0 += x1; x1 = (x1 << (r)) | (x1 >> (32 - (r))); x1 ^= x0; }
  x0 += k0; x1 += k1;
  TFR(13) TFR(15) TFR(26) TFR(6)
  x0 += k1; x1 += k2 + 1u;
  TFR(17) TFR(29) TFR(16) TFR(24)
  x0 += k2; x1 += k0 + 2u;
  TFR(13) TFR(15) TFR(26) TFR(6)
  x0 += k0; x1 += k1 + 3u;
  TFR(17) TFR(29) TFR(16) TFR(24)
  x0 += k1; x1 += k2 + 4u;
  TFR(13) TFR(15) TFR(26) TFR(6)
  x0 += k2; x1 += k0 + 5u;
#undef TFR
  o0 = x0; o1 = x1;
}

// XLA ErfInv (f32), Giles polynomial
__device__ inline float erfinv_f32(float x) {
  float w = -log1pf(-x * x);
  float p;
  if (w < 5.0f) {
    w = w - 2.5f;
    p = 2.81022636e-08f;
    p = 3.43273939e-07f + p * w;
    p = -3.5233877e-06f + p * w;
    p = -4.39150654e-06f + p * w;
    p = 0.00021858087f + p * w;
    p = -0.00125372503f + p * w;
    p = -0.00417768164f + p * w;
    p = 0.246640727f + p * w;
    p = 1.50140941f + p * w;
  } else {
    w = sqrtf(w) - 3.0f;
    p = -0.000200214257f;
    p = 0.000100950558f + p * w;
    p = 0.00134934322f + p * w;
    p = -0.00367342844f + p * w;
    p = 0.00573950773f + p * w;
    p = -0.0076224613f + p * w;
    p = 0.00943887047f + p * w;
    p = 1.00167406f + p * w;
    p = 2.83297682f + p * w;
  }
  return p * x;
}

__device__ inline float bits_to_f01(uint32_t bits) {
  uint32_t fb = (bits >> 9) | 0x3F800000u;
  return __uint_as_float(fb) - 1.0f;
}

// wave-uniform broadcast via v_readlane (bit-identical to __shfl for uniform
// lane index with all lanes active; lands in SGPR)
__device__ inline float readlane_f(float v, int lane) {
  return __int_as_float(__builtin_amdgcn_readlane(__float_as_int(v), lane));
}

// ---------------- K1: emb + pixel_probs + per-block partial sums -----------
// partial layout: [b*EBLK+bb][17][196]  (j-major, g coalesced)
__global__ __launch_bounds__(256) void emb_kernel(
    const float* __restrict__ x, const int* __restrict__ groups,
    const float* __restrict__ Wc, const float* __restrict__ bc,
    float* __restrict__ partial, float* __restrict__ pixel_probs) {
  __shared__ float lsum[NSEG * 17];
  int b = blockIdx.x / EBLK;
  int blk = blockIdx.x % EBLK;
  int tid = threadIdx.x;
  for (int i = tid; i < NSEG * 17; i += 256) lsum[i] = 0.0f;
  __syncthreads();
  const float* xb = x + (size_t)b * 3 * HW;
  for (int k = 0; k < PXB / 256; ++k) {
    int p = blk * PXB + k * 256 + tid;
    float x0 = xb[p], x1 = xb[HW + p], x2 = xb[2 * HW + p];
    int g = groups[b * HW + p];
    float* dst = lsum + g * 17;
#pragma unroll
    for (int j = 0; j < EMB; ++j) {
      float e = Wc[j * 3 + 0] * x0 + Wc[j * 3 + 1] * x1;
      e = e + Wc[j * 3 + 2] * x2 + bc[j];
      if (j == 0) pixel_probs[b * HW + p] = 1.0f / (1.0f + expf(-e));
      atomicAdd(&dst[j], e);
    }
    atomicAdd(&dst[16], 1.0f);
  }
  __syncthreads();
  // transposed coalesced flush (no global atomics)
  float* pb = partial + (size_t)blockIdx.x * (17 * NSEG);
  if (tid < NSEG) {
#pragma unroll
    for (int j = 0; j < 17; ++j) pb[j * NSEG + tid] = lsum[tid * 17 + j];
  }
}

// ---------------- K2: stats — mu, group_probs, G (column-major) ------------
__global__ __launch_bounds__(256) void stats_kernel(
    const float* __restrict__ partial, float* __restrict__ mu_ws,
    float* __restrict__ group_probs, float* __restrict__ Gc /* [B][15][196] */) {
  int b = blockIdx.x;
  int i = threadIdx.x;
  if (i >= NSEG) return;
  float acc[17];
#pragma unroll
  for (int j = 0; j < 17; ++j) acc[j] = 0.0f;
  for (int bb = 0; bb < EBLK; ++bb) {
    const float* pb = partial + (size_t)(b * EBLK + bb) * (17 * NSEG);
#pragma unroll
    for (int j = 0; j < 17; ++j) acc[j] += pb[j * NSEG + i];
  }
  float denom = fmaxf(acc[16], 1.0f);
  float m = acc[0] / denom;
  mu_ws[b * NSEG + i] = m;
  group_probs[b * NSEG + i] = 1.0f / (1.0f + expf(-m));
#pragma unroll
  for (int j = 0; j < 15; ++j)
    Gc[((size_t)b * 15 + j) * NSEG + i] = acc[j + 1] / denom;
}

// ---------------- K3: sigma = G G^T + jitter*I (tiled) ---------------------
__global__ __launch_bounds__(256) void sigma_kernel(
    const float* __restrict__ Gc, float* __restrict__ sigma_out) {
  int b = blockIdx.x / 7;
  int tile = blockIdx.x % 7;
  int tid = threadIdx.x;
  __shared__ float ge[15][NSEG];
  if (tid < NSEG) {
#pragma unroll
    for (int j = 0; j < 15; ++j) ge[j][tid] = Gc[((size_t)b * 15 + j) * NSEG + tid];
  }
  __syncthreads();
  if (tid >= NSEG) return;
  int t = tid;
  for (int r = 0; r < 28; ++r) {
    int s = tile * 28 + r;
    float acc = 0.0f;
#pragma unroll
    for (int j = 0; j < 15; ++j) acc = fmaf(ge[j][s], ge[j][t], acc);
    if (s == t) acc += JITTER;
    sigma_out[((size_t)b * NSEG + s) * NSEG + t] = acc;
  }
}

// ---------------- K4: fused rng + low-rank Cholesky + L@eps + hard ---------
// sigma = jitter*I + G G^T.  Schur invariant keeps only G (rank 15) as state:
//   d = sqrt(j + |g_k|^2); L[i,k] = g_i.g_k/d; g_i -= beta (g_i.g_k) g_k,
//   beta = 1/(d(d+sqrt(j))).
// 4 waves/block, each wave replicates the recurrence and owns a 4-wide MC
// slice.  Row-k broadcast via v_readlane into SGPRs.  Four compile-time
// phases (round-9).  THIS ROUND: select-chains stripped from non-pivot
// slots — for s > P every live row has i > k, and dead rows (i >= NSEG)
// have g identically +0 so dot = +0 and w = dot*invd = +0; fmaf(+/-0, ek,
// acc) == acc exactly, and the downdate keeps zero rows at +0.  Only the
// pivot slot needs the 3-way select, done on lane/owner ints.  Bit-identical
// to rounds 2/5/8/9 (passing).  Slots use COMPILE-TIME indices only
// (round-3 scratch regression).
__global__ __launch_bounds__(256, 1) void cholmc_kernel(
    const float* __restrict__ Gc, const float* __restrict__ mu,
    uint32_t kg0, uint32_t kg1, uint32_t ku0, uint32_t ku1,
    float* __restrict__ hard) {
  int b = blockIdx.x;
  int tid = threadIdx.x;
  int lane = tid & 63;
  int wave = tid >> 6;
  __shared__ float eps_lds[NSEG * MC];  // 12.25 KB

  // prologue: eps = sqrt(2)*erfinv(bits) straight into LDS
  for (int t = tid; t < NSEG * MC; t += 256) {
    uint32_t a0, a1;
    threefry2x32(kg0, kg1, 0u, (uint32_t)(b * NSEG * MC + t), a0, a1);
    float f = bits_to_f01(a0 ^ a1);
    const float lo = -0.99999994f;  // nextafter(-1,0)
    float u = fmaxf(lo, f * (1.0f - lo) + lo);
    eps_lds[t] = 1.4142135623730951f * erfinv_f32(u);
  }

  float g[4][15];
  float acc[4][4];
#pragma unroll
  for (int s = 0; s < 4; ++s) {
    int i = s * 64 + lane;
#pragma unroll
    for (int j = 0; j < 15; ++j)
      g[s][j] = (i < NSEG) ? Gc[((size_t)b * 15 + j) * NSEG + i] : 0.0f;
#pragma unroll
    for (int q = 0; q < 4; ++q) acc[s][q] = 0.0f;
  }
  __syncthreads();

  const float sj = 0.031622776601683794f;  // sqrt(jitter)

// One phase: pivot slot P is a compile-time literal.  Non-pivot slots carry
// no compares (see header comment); pivot slot selects on lane vs owner.
#define CHOL_PHASE(P, KBEG, KEND)                                          \
  for (int k = (KBEG); k < (KEND); ++k) {                                  \
    const float4 ekv = *(const float4*)(eps_lds + k * MC + wave * 4);      \
    int owner = k & 63;                                                    \
    float gk[15];                                                          \
    _Pragma("unroll")                                                      \
    for (int j = 0; j < 15; ++j) gk[j] = readlane_f(g[P][j], owner);       \
    float nrm = 0.0f;                                                      \
    _Pragma("unroll")                                                      \
    for (int j = 0; j < 15; ++j) nrm = fmaf(gk[j], gk[j], nrm);            \
    float dd = sqrtf(JITTER + nrm);                                        \
    float invd = 1.0f / dd;                                                \
    float beta = 1.0f / (dd * (dd + sj));                                  \
    float ek[4] = {ekv.x, ekv.y, ekv.z, ekv.w};                            \
    { /* pivot slot */                                                     \
      float dot = 0.0f;                                                    \
      _Pragma("unroll")                                                    \
      for (int j = 0; j < 15; ++j) dot = fmaf(g[P][j], gk[j], dot);        \
      float w = (lane > owner) ? dot * invd                                \
                               : ((lane == owner) ? dd : 0.0f);            \
      _Pragma("unroll")                                                    \
      for (int q = 0; q < 4; ++q) acc[P][q] = fmaf(w, ek[q], acc[P][q]);   \
      float bd = beta * dot;                                               \
      _Pragma("unroll")                                                    \
      for (int j = 0; j < 15; ++j) g[P][j] = fmaf(-bd, gk[j], g[P][j]);    \
    }                                                                      \
    _Pragma("unroll")                                                      \
    for (int s = (P) + 1; s < 4; ++s) { /* compile-time s */               \
      float dot = 0.0f;                                                    \
      _Pragma("unroll")                                                    \
      for (int j = 0; j < 15; ++j) dot = fmaf(g[s][j], gk[j], dot);        \
      float w = dot * invd;  /* i>k always; zero rows stay +0 */           \
      _Pragma("unroll")                                                    \
      for (int q = 0; q < 4; ++q) acc[s][q] = fmaf(w, ek[q], acc[s][q]);   \
      float bd = beta * dot;                                               \
      _Pragma("unroll")                                                    \
      for (int j = 0; j < 15; ++j) g[s][j] = fmaf(-bd, gk[j], g[s][j]);    \
    }                                                                      \
  }

  CHOL_PHASE(0, 0, 64)
  CHOL_PHASE(1, 64, 128)
  CHOL_PHASE(2, 128, 192)
  CHOL_PHASE(3, 192, 196)
#undef CHOL_PHASE

  // epilogue: hard = (mu + L@eps + logistic) > 0, this wave's m-slice
#pragma unroll
  for (int s = 0; s < 4; ++s) {
    int i = s * 64 + lane;
    if (i < NSEG) {
      float mui = mu[b * NSEG + i];
      float4 outv;
      float* op = (float*)&outv;
#pragma unroll
      for (int q = 0; q < 4; ++q) {
        int m = wave * 4 + q;
        uint32_t a0, a1;
        threefry2x32(ku0, ku1, 0u, (uint32_t)(b * NSEG * MC + i * MC + m), a0, a1);
        float f = bits_to_f01(a0 ^ a1);
        const float mn = 1e-6f;
        const float mx = (float)(1.0 - 1e-6);
        float uu = fmaxf(mn, f * (mx - mn) + mn);
        float lg = logf(uu) - log1pf(-uu);
        float z = mui + acc[s][q] + lg;
        op[q] = (z > 0.0f) ? 1.0f : 0.0f;
      }
      *(float4*)(hard + ((size_t)b * NSEG + i) * MC + wave * 4) = outv;
    }
  }
}

// ---------------- K5: mask gather, one float4 per thread -------------------
__global__ __launch_bounds__(256) void mask_kernel(
    const int* __restrict__ groups, const float* __restrict__ hard,
    float4* __restrict__ out) {
  int f = blockIdx.x * blockDim.x + threadIdx.x;  // float4 index
  if (f >= BATCH * 3 * HW * 4) return;
  int pix = f >> 2;          // (b*3+c)*HW + p
  int q = f & 3;
  int b = pix / (3 * HW);
  int p = pix % HW;
  int g = groups[b * HW + p];
  out[f] = ((const float4*)hard)[(b * NSEG + g) * 4 + q];
}

extern "C" void kernel_launch(void* const* d_in, const int* in_sizes, int n_in,
                              void* d_out, int out_size, void* d_ws, size_t ws_size,
                              hipStream_t stream) {
  const float* x = (const float*)d_in[0];
  const int* groups = (const int*)d_in[1];
  const float* Wc = (const float*)d_in[2];
  const float* bc = (const float*)d_in[3];

  float* out = (float*)d_out;
  float* mask_out = out;                         // 38,535,168
  float* gp_out = out + 38535168;                //      3,136
  float* pp_out = gp_out + 3136;                 //    802,816
  float* sig_out = pp_out + 802816;              //    614,656

  float* ws = (float*)d_ws;
  float* partial = ws;                           // 224*3332 = 746,368
  float* mu_ws = ws + 746368;                    //   3,136
  float* Gc    = ws + 749504;                    //  47,040  (tot 3.19 MB)
  float* hard  = ws;                             // 50,176 — reuses dead partial

  emb_kernel<<<BATCH * EBLK, 256, 0, stream>>>(x, groups, Wc, bc, partial, pp_out);
  stats_kernel<<<BATCH, 256, 0, stream>>>(partial, mu_ws, gp_out, Gc);
  sigma_kernel<<<BATCH * 7, 256, 0, stream>>>(Gc, sig_out);

  uint32_t kg0, kg1, ku0, ku1;
  threefry2x32(0u, 42u, 0u, 0u, kg0, kg1);
  threefry2x32(0u, 42u, 0u, 1u, ku0, ku1);

  cholmc_kernel<<<BATCH, 256, 0, stream>>>(Gc, mu_ws, kg0, kg1, ku0, ku1, hard);
  mask_kernel<<<(BATCH * 3 * HW * 4 + 255) / 256, 256, 0, stream>>>(
      groups, hard, (float4*)mask_out);
}

// Round 11
// 339.515 us; speedup vs baseline: 1.1525x; 1.0290x over previous
//
#include <hip/hip_runtime.h>
#include <stdint.h>

#define HW    50176   // 224*224
#define BATCH 16
#define NSEG  196
#define EMB   16
#define MC    16
#define JITTER 0.001f
#define EBLK  14      // emb blocks per batch
#define PXB   3584    // pixels per emb block (50176/14)

// ---------------- threefry2x32 (20 rounds), bit-exact vs JAX ----------------
__host__ __device__ inline void threefry2x32(uint32_t k0, uint32_t k1,
                                             uint32_t x0, uint32_t x1,
                                             uint32_t& o0, uint32_t& o1) {
  uint32_t k2 = k0 ^ k1 ^ 0x1BD11BDAu;
#define TFR(r) { x0 += x1; x1 = (x1 << (r)) | (x1 >> (32 - (r))); x1 ^= x0; }
  x0 += k0; x1 += k1;
  TFR(13) TFR(15) TFR(26) TFR(6)
  x0 += k1; x1 += k2 + 1u;
  TFR(17) TFR(29) TFR(16) TFR(24)
  x0 += k2; x1 += k0 + 2u;
  TFR(13) TFR(15) TFR(26) TFR(6)
  x0 += k0; x1 += k1 + 3u;
  TFR(17) TFR(29) TFR(16) TFR(24)
  x0 += k1; x1 += k2 + 4u;
  TFR(13) TFR(15) TFR(26) TFR(6)
  x0 += k2; x1 += k0 + 5u;
#undef TFR
  o0 = x0; o1 = x1;
}

// XLA ErfInv (f32), Giles polynomial
__device__ inline float erfinv_f32(float x) {
  float w = -log1pf(-x * x);
  float p;
  if (w < 5.0f) {
    w = w - 2.5f;
    p = 2.81022636e-08f;
    p = 3.43273939e-07f + p * w;
    p = -3.5233877e-06f + p * w;
    p = -4.39150654e-06f + p * w;
    p = 0.00021858087f + p * w;
    p = -0.00125372503f + p * w;
    p = -0.00417768164f + p * w;
    p = 0.246640727f + p * w;
    p = 1.50140941f + p * w;
  } else {
    w = sqrtf(w) - 3.0f;
    p = -0.000200214257f;
    p = 0.000100950558f + p * w;
    p = 0.00134934322f + p * w;
    p = -0.00367342844f + p * w;
    p = 0.00573950773f + p * w;
    p = -0.0076224613f + p * w;
    p = 0.00943887047f + p * w;
    p = 1.00167406f + p * w;
    p = 2.83297682f + p * w;
  }
  return p * x;
}

__device__ inline float bits_to_f01(uint32_t bits) {
  uint32_t fb = (bits >> 9) | 0x3F800000u;
  return __uint_as_float(fb) - 1.0f;
}

// wave-uniform broadcast via v_readlane (bit-identical to __shfl for uniform
// lane index with all lanes active; lands in SGPR)
__device__ inline float readlane_f(float v, int lane) {
  return __int_as_float(__builtin_amdgcn_readlane(__float_as_int(v), lane));
}

// ---------------- K1: emb + pixel_probs + per-block partial sums -----------
// partial layout: [b*EBLK+bb][17][196]  (j-major, g coalesced)
__global__ __launch_bounds__(256) void emb_kernel(
    const float* __restrict__ x, const int* __restrict__ groups,
    const float* __restrict__ Wc, const float* __restrict__ bc,
    float* __restrict__ partial, float* __restrict__ pixel_probs) {
  __shared__ float lsum[NSEG * 17];
  int b = blockIdx.x / EBLK;
  int blk = blockIdx.x % EBLK;
  int tid = threadIdx.x;
  for (int i = tid; i < NSEG * 17; i += 256) lsum[i] = 0.0f;
  __syncthreads();
  const float* xb = x + (size_t)b * 3 * HW;
  for (int k = 0; k < PXB / 256; ++k) {
    int p = blk * PXB + k * 256 + tid;
    float x0 = xb[p], x1 = xb[HW + p], x2 = xb[2 * HW + p];
    int g = groups[b * HW + p];
    float* dst = lsum + g * 17;
#pragma unroll
    for (int j = 0; j < EMB; ++j) {
      float e = Wc[j * 3 + 0] * x0 + Wc[j * 3 + 1] * x1;
      e = e + Wc[j * 3 + 2] * x2 + bc[j];
      if (j == 0) pixel_probs[b * HW + p] = 1.0f / (1.0f + expf(-e));
      atomicAdd(&dst[j], e);
    }
    atomicAdd(&dst[16], 1.0f);
  }
  __syncthreads();
  // transposed coalesced flush (no global atomics)
  float* pb = partial + (size_t)blockIdx.x * (17 * NSEG);
  if (tid < NSEG) {
#pragma unroll
    for (int j = 0; j < 17; ++j) pb[j * NSEG + tid] = lsum[tid * 17 + j];
  }
}

// ---------------- K2: stats — mu, group_probs, G (column-major) ------------
__global__ __launch_bounds__(256) void stats_kernel(
    const float* __restrict__ partial, float* __restrict__ mu_ws,
    float* __restrict__ group_probs, float* __restrict__ Gc /* [B][15][196] */) {
  int b = blockIdx.x;
  int i = threadIdx.x;
  if (i >= NSEG) return;
  float acc[17];
#pragma unroll
  for (int j = 0; j < 17; ++j) acc[j] = 0.0f;
  for (int bb = 0; bb < EBLK; ++bb) {
    const float* pb = partial + (size_t)(b * EBLK + bb) * (17 * NSEG);
#pragma unroll
    for (int j = 0; j < 17; ++j) acc[j] += pb[j * NSEG + i];
  }
  float denom = fmaxf(acc[16], 1.0f);
  float m = acc[0] / denom;
  mu_ws[b * NSEG + i] = m;
  group_probs[b * NSEG + i] = 1.0f / (1.0f + expf(-m));
#pragma unroll
  for (int j = 0; j < 15; ++j)
    Gc[((size_t)b * 15 + j) * NSEG + i] = acc[j + 1] / denom;
}

// ---------------- K3: sigma = G G^T + jitter*I (tiled) ---------------------
__global__ __launch_bounds__(256) void sigma_kernel(
    const float* __restrict__ Gc, float* __restrict__ sigma_out) {
  int b = blockIdx.x / 7;
  int tile = blockIdx.x % 7;
  int tid = threadIdx.x;
  __shared__ float ge[15][NSEG];
  if (tid < NSEG) {
#pragma unroll
    for (int j = 0; j < 15; ++j) ge[j][tid] = Gc[((size_t)b * 15 + j) * NSEG + tid];
  }
  __syncthreads();
  if (tid >= NSEG) return;
  int t = tid;
  for (int r = 0; r < 28; ++r) {
    int s = tile * 28 + r;
    float acc = 0.0f;
#pragma unroll
    for (int j = 0; j < 15; ++j) acc = fmaf(ge[j][s], ge[j][t], acc);
    if (s == t) acc += JITTER;
    sigma_out[((size_t)b * NSEG + s) * NSEG + t] = acc;
  }
}

// ---------------- K4: fused rng + low-rank Cholesky + L@eps + hard ---------
// sigma = jitter*I + G G^T.  Schur invariant keeps only G (rank 15) as state:
//   d = sqrt(j + |g_k|^2); L[i,k] = g_i.g_k/d; g_i -= beta (g_i.g_k) g_k,
//   beta = 1/(d(d+sqrt(j))).
// 4 waves/block, each wave replicates the recurrence and owns a 4-wide MC
// slice.  Row-k broadcast via v_readlane into SGPRs.  Four compile-time
// phases (round-9); no compares in non-pivot slots (round-10).
// THIS ROUND (latency-bound per R8/R9/R10 evidence: instruction cuts were
// neutral, so the serial chain is the clock): the wave-uniform scalar
// sub-chain is shortened —
//   * |g_k|^2 via pairwise TREE (depth 5) instead of 15 serial fmas,
//   * v_rsq + v_rcp replace IEEE sqrt + two IEEE divides:
//       invd = rsq(jn); dd = jn*invd; beta = invd^2 * rcp(1 + sj*invd)
//     (algebra: 1/(dd(dd+sj)) = invd^2/(1+sj*invd)).
// Perturbation is ~2-4 ulp RELATIVE on d/invd/beta, recomputed fresh each
// step (no accumulation — unlike round-6's incremental-nsq failure).  The
// dot/acc/update fma chains are bit-identical to rounds 9/10.
// Slots use COMPILE-TIME indices only (round-3 scratch regression).
__global__ __launch_bounds__(256, 1) void cholmc_kernel(
    const float* __restrict__ Gc, const float* __restrict__ mu,
    uint32_t kg0, uint32_t kg1, uint32_t ku0, uint32_t ku1,
    float* __restrict__ hard) {
  int b = blockIdx.x;
  int tid = threadIdx.x;
  int lane = tid & 63;
  int wave = tid >> 6;
  __shared__ float eps_lds[NSEG * MC];  // 12.25 KB

  // prologue: eps = sqrt(2)*erfinv(bits) straight into LDS
  for (int t = tid; t < NSEG * MC; t += 256) {
    uint32_t a0, a1;
    threefry2x32(kg0, kg1, 0u, (uint32_t)(b * NSEG * MC + t), a0, a1);
    float f = bits_to_f01(a0 ^ a1);
    const float lo = -0.99999994f;  // nextafter(-1,0)
    float u = fmaxf(lo, f * (1.0f - lo) + lo);
    eps_lds[t] = 1.4142135623730951f * erfinv_f32(u);
  }

  float g[4][15];
  float acc[4][4];
#pragma unroll
  for (int s = 0; s < 4; ++s) {
    int i = s * 64 + lane;
#pragma unroll
    for (int j = 0; j < 15; ++j)
      g[s][j] = (i < NSEG) ? Gc[((size_t)b * 15 + j) * NSEG + i] : 0.0f;
#pragma unroll
    for (int q = 0; q < 4; ++q) acc[s][q] = 0.0f;
  }
  __syncthreads();

  const float sj = 0.031622776601683794f;  // sqrt(jitter)

// One phase: pivot slot P is a compile-time literal.  Non-pivot slots carry
// no compares; pivot slot selects on lane/owner ints.  Scalar chain uses
// tree-norm + rsq/rcp (see kernel header).
#define CHOL_PHASE(P, KBEG, KEND)                                          \
  for (int k = (KBEG); k < (KEND); ++k) {                                  \
    const float4 ekv = *(const float4*)(eps_lds + k * MC + wave * 4);      \
    int owner = k & 63;                                                    \
    float gk[15];                                                          \
    _Pragma("unroll")                                                      \
    for (int j = 0; j < 15; ++j) gk[j] = readlane_f(g[P][j], owner);       \
    /* pairwise tree norm, JITTER folded into leaf 0 (depth ~5) */         \
    float t0 = fmaf(gk[0], gk[0], JITTER);                                 \
    float t1 = gk[1] * gk[1];   float t2 = gk[2] * gk[2];                  \
    float t3 = gk[3] * gk[3];   float t4 = gk[4] * gk[4];                  \
    float t5 = gk[5] * gk[5];   float t6 = gk[6] * gk[6];                  \
    float t7 = gk[7] * gk[7];   float t8 = gk[8] * gk[8];                  \
    float t9 = gk[9] * gk[9];   float t10 = gk[10] * gk[10];               \
    float t11 = gk[11] * gk[11]; float t12 = gk[12] * gk[12];              \
    float t13 = gk[13] * gk[13]; float t14 = gk[14] * gk[14];              \
    float u0 = t0 + t1, u1 = t2 + t3, u2 = t4 + t5, u3 = t6 + t7;          \
    float u4 = t8 + t9, u5 = t10 + t11, u6 = t12 + t13;                    \
    float v0 = u0 + u1, v1 = u2 + u3, v2 = u4 + u5, v3 = u6 + t14;         \
    float jn = (v0 + v1) + (v2 + v3);                                      \
    float invd = __builtin_amdgcn_rsqf(jn);                                \
    float dd = jn * invd;                                                  \
    float beta = (invd * invd) * __builtin_amdgcn_rcpf(fmaf(sj, invd, 1.0f)); \
    float ek[4] = {ekv.x, ekv.y, ekv.z, ekv.w};                            \
    { /* pivot slot */                                                     \
      float dot = 0.0f;                                                    \
      _Pragma("unroll")                                                    \
      for (int j = 0; j < 15; ++j) dot = fmaf(g[P][j], gk[j], dot);        \
      float w = (lane > owner) ? dot * invd                                \
                               : ((lane == owner) ? dd : 0.0f);            \
      _Pragma("unroll")                                                    \
      for (int q = 0; q < 4; ++q) acc[P][q] = fmaf(w, ek[q], acc[P][q]);   \
      float bd = beta * dot;                                               \
      _Pragma("unroll")                                                    \
      for (int j = 0; j < 15; ++j) g[P][j] = fmaf(-bd, gk[j], g[P][j]);    \
    }                                                                      \
    _Pragma("unroll")                                                      \
    for (int s = (P) + 1; s < 4; ++s) { /* compile-time s */               \
      float dot = 0.0f;                                                    \
      _Pragma("unroll")                                                    \
      for (int j = 0; j < 15; ++j) dot = fmaf(g[s][j], gk[j], dot);        \
      float w = dot * invd;  /* i>k always; zero rows stay +0 */           \
      _Pragma("unroll")                                                    \
      for (int q = 0; q < 4; ++q) acc[s][q] = fmaf(w, ek[q], acc[s][q]);   \
      float bd = beta * dot;                                               \
      _Pragma("unroll")                                                    \
      for (int j = 0; j < 15; ++j) g[s][j] = fmaf(-bd, gk[j], g[s][j]);    \
    }                                                                      \
  }

  CHOL_PHASE(0, 0, 64)
  CHOL_PHASE(1, 64, 128)
  CHOL_PHASE(2, 128, 192)
  CHOL_PHASE(3, 192, 196)
#undef CHOL_PHASE

  // epilogue: hard = (mu + L@eps + logistic) > 0, this wave's m-slice
#pragma unroll
  for (int s = 0; s < 4; ++s) {
    int i = s * 64 + lane;
    if (i < NSEG) {
      float mui = mu[b * NSEG + i];
      float4 outv;
      float* op = (float*)&outv;
#pragma unroll
      for (int q = 0; q < 4; ++q) {
        int m = wave * 4 + q;
        uint32_t a0, a1;
        threefry2x32(ku0, ku1, 0u, (uint32_t)(b * NSEG * MC + i * MC + m), a0, a1);
        float f = bits_to_f01(a0 ^ a1);
        const float mn = 1e-6f;
        const float mx = (float)(1.0 - 1e-6);
        float uu = fmaxf(mn, f * (mx - mn) + mn);
        float lg = logf(uu) - log1pf(-uu);
        float z = mui + acc[s][q] + lg;
        op[q] = (z > 0.0f) ? 1.0f : 0.0f;
      }
      *(float4*)(hard + ((size_t)b * NSEG + i) * MC + wave * 4) = outv;
    }
  }
}

// ---------------- K5: mask gather, one float4 per thread -------------------
__global__ __launch_bounds__(256) void mask_kernel(
    const int* __restrict__ groups, const float* __restrict__ hard,
    float4* __restrict__ out) {
  int f = blockIdx.x * blockDim.x + threadIdx.x;  // float4 index
  if (f >= BATCH * 3 * HW * 4) return;
  int pix = f >> 2;          // (b*3+c)*HW + p
  int q = f & 3;
  int b = pix / (3 * HW);
  int p = pix % HW;
  int g = groups[b * HW + p];
  out[f] = ((const float4*)hard)[(b * NSEG + g) * 4 + q];
}

extern "C" void kernel_launch(void* const* d_in, const int* in_sizes, int n_in,
                              void* d_out, int out_size, void* d_ws, size_t ws_size,
                              hipStream_t stream) {
  const float* x = (const float*)d_in[0];
  const int* groups = (const int*)d_in[1];
  const float* Wc = (const float*)d_in[2];
  const float* bc = (const float*)d_in[3];

  float* out = (float*)d_out;
  float* mask_out = out;                         // 38,535,168
  float* gp_out = out + 38535168;                //      3,136
  float* pp_out = gp_out + 3136;                 //    802,816
  float* sig_out = pp_out + 802816;              //    614,656

  float* ws = (float*)d_ws;
  float* partial = ws;                           // 224*3332 = 746,368
  float* mu_ws = ws + 746368;                    //   3,136
  float* Gc    = ws + 749504;                    //  47,040  (tot 3.19 MB)
  float* hard  = ws;                             // 50,176 — reuses dead partial

  emb_kernel<<<BATCH * EBLK, 256, 0, stream>>>(x, groups, Wc, bc, partial, pp_out);
  stats_kernel<<<BATCH, 256, 0, stream>>>(partial, mu_ws, gp_out, Gc);
  sigma_kernel<<<BATCH * 7, 256, 0, stream>>>(Gc, sig_out);

  uint32_t kg0, kg1, ku0, ku1;
  threefry2x32(0u, 42u, 0u, 0u, kg0, kg1);
  threefry2x32(0u, 42u, 0u, 1u, ku0, ku1);

  cholmc_kernel<<<BATCH, 256, 0, stream>>>(Gc, mu_ws, kg0, kg1, ku0, ku1, hard);
  mask_kernel<<<(BATCH * 3 * HW * 4 + 255) / 256, 256, 0, stream>>>(
      groups, hard, (float4*)mask_out);
}

// Round 12
// 269.851 us; speedup vs baseline: 1.4500x; 1.2582x over previous
//
#include <hip/hip_runtime.h>
#include <stdint.h>

#define HW    50176   // 224*224
#define BATCH 16
#define NSEG  196
#define EMB   16
#define MC    16
#define JITTER 0.001f
#define EBLK  14      // emb blocks per batch
#define PXB   3584    // pixels per emb block (50176/14)

// ---------------- threefry2x32 (20 rounds), bit-exact vs JAX ----------------
__host__ __device__ inline void threefry2x32(uint32_t k0, uint32_t k1,
                                             uint32_t x0, uint32_t x1,
                                             uint32_t& o0, uint32_t& o1) {
  uint32_t k2 = k0 ^ k1 ^ 0x1BD11BDAu;
#define TFR(r) { x0 += x1; x1 = (x1 << (r)) | (x1 >> (32 - (r))); x1 ^= x0; }
  x0 += k0; x1 += k1;
  TFR(13) TFR(15) TFR(26) TFR(6)
  x0 += k1; x1 += k2 + 1u;
  TFR(17) TFR(29) TFR(16) TFR(24)
  x0 += k2; x1 += k0 + 2u;
  TFR(13) TFR(15) TFR(26) TFR(6)
  x0 += k0; x1 += k1 + 3u;
  TFR(17) TFR(29) TFR(16) TFR(24)
  x0 += k1; x1 += k2 + 4u;
  TFR(13) TFR(15) TFR(26) TFR(6)
  x0 += k2; x1 += k0 + 5u;
#undef TFR
  o0 = x0; o1 = x1;
}

// XLA ErfInv (f32), Giles polynomial
__device__ inline float erfinv_f32(float x) {
  float w = -log1pf(-x * x);
  float p;
  if (w < 5.0f) {
    w = w - 2.5f;
    p = 2.81022636e-08f;
    p = 3.43273939e-07f + p * w;
    p = -3.5233877e-06f + p * w;
    p = -4.39150654e-06f + p * w;
    p = 0.00021858087f + p * w;
    p = -0.00125372503f + p * w;
    p = -0.00417768164f + p * w;
    p = 0.246640727f + p * w;
    p = 1.50140941f + p * w;
  } else {
    w = sqrtf(w) - 3.0f;
    p = -0.000200214257f;
    p = 0.000100950558f + p * w;
    p = 0.00134934322f + p * w;
    p = -0.00367342844f + p * w;
    p = 0.00573950773f + p * w;
    p = -0.0076224613f + p * w;
    p = 0.00943887047f + p * w;
    p = 1.00167406f + p * w;
    p = 2.83297682f + p * w;
  }
  return p * x;
}

__device__ inline float bits_to_f01(uint32_t bits) {
  uint32_t fb = (bits >> 9) | 0x3F800000u;
  return __uint_as_float(fb) - 1.0f;
}

// ---------------- K1: pixel_probs + per-block segment sums of x,cnt --------
// Linearity: sum_emb_j[g] = W[j,:].sum_x[g] + b_j*cnt[g], so we only
// accumulate the 3 input channels + count (4 LDS atomics/pixel vs 17).
// partial layout: [b*EBLK+bb][4][196]  (c-major, g coalesced)
__global__ __launch_bounds__(256) void emb_kernel(
    const float* __restrict__ x, const int* __restrict__ groups,
    const float* __restrict__ Wc, const float* __restrict__ bc,
    float* __restrict__ partial, float* __restrict__ pixel_probs) {
  __shared__ float lsum[4 * NSEG];  // [c][g]
  int b = blockIdx.x / EBLK;
  int blk = blockIdx.x % EBLK;
  int tid = threadIdx.x;
  for (int i = tid; i < 4 * NSEG; i += 256) lsum[i] = 0.0f;
  __syncthreads();
  const float* xb = x + (size_t)b * 3 * HW;
  float w0 = Wc[0], w1 = Wc[1], w2 = Wc[2], b0 = bc[0];
  for (int k = 0; k < PXB / 256; ++k) {
    int p = blk * PXB + k * 256 + tid;
    float x0 = xb[p], x1 = xb[HW + p], x2 = xb[2 * HW + p];
    int g = groups[b * HW + p];
    float e = w0 * x0 + w1 * x1;      // same expression shape as before
    e = e + w2 * x2 + b0;
    pixel_probs[b * HW + p] = 1.0f / (1.0f + expf(-e));
    atomicAdd(&lsum[g], x0);
    atomicAdd(&lsum[NSEG + g], x1);
    atomicAdd(&lsum[2 * NSEG + g], x2);
    atomicAdd(&lsum[3 * NSEG + g], 1.0f);
  }
  __syncthreads();
  float* pb = partial + (size_t)blockIdx.x * (4 * NSEG);
  if (tid < NSEG) {
#pragma unroll
    for (int c = 0; c < 4; ++c) pb[c * NSEG + tid] = lsum[c * NSEG + tid];
  }
}

// ---------------- K2: stats — mu, group_probs, G via linearity -------------
__global__ __launch_bounds__(256) void stats_kernel(
    const float* __restrict__ partial, const float* __restrict__ Wc,
    const float* __restrict__ bc, float* __restrict__ mu_ws,
    float* __restrict__ group_probs, float* __restrict__ Gc /* [B][15][196] */) {
  int b = blockIdx.x;
  int i = threadIdx.x;
  if (i >= NSEG) return;
  float sx0 = 0.0f, sx1 = 0.0f, sx2 = 0.0f, cn = 0.0f;
  for (int bb = 0; bb < EBLK; ++bb) {
    const float* pb = partial + (size_t)(b * EBLK + bb) * (4 * NSEG);
    sx0 += pb[i]; sx1 += pb[NSEG + i]; sx2 += pb[2 * NSEG + i]; cn += pb[3 * NSEG + i];
  }
  float denom = fmaxf(cn, 1.0f);
#pragma unroll
  for (int j = 0; j < EMB; ++j) {
    float e = Wc[j * 3 + 0] * sx0 + Wc[j * 3 + 1] * sx1;
    e = e + Wc[j * 3 + 2] * sx2 + bc[j] * cn;
    float v = e / denom;
    if (j == 0) {
      mu_ws[b * NSEG + i] = v;
      group_probs[b * NSEG + i] = 1.0f / (1.0f + expf(-v));
    } else {
      Gc[((size_t)b * 15 + (j - 1)) * NSEG + i] = v;
    }
  }
}

// ---------------- K3: sigma = G G^T + jitter*I (tiled) ---------------------
__global__ __launch_bounds__(256) void sigma_kernel(
    const float* __restrict__ Gc, float* __restrict__ sigma_out) {
  int b = blockIdx.x / 7;
  int tile = blockIdx.x % 7;
  int tid = threadIdx.x;
  __shared__ float ge[15][NSEG];
  if (tid < NSEG) {
#pragma unroll
    for (int j = 0; j < 15; ++j) ge[j][tid] = Gc[((size_t)b * 15 + j) * NSEG + tid];
  }
  __syncthreads();
  if (tid >= NSEG) return;
  int t = tid;
  float gt[15];
#pragma unroll
  for (int j = 0; j < 15; ++j) gt[j] = ge[j][t];
  for (int r = 0; r < 28; ++r) {
    int s = tile * 28 + r;
    float acc = 0.0f;
#pragma unroll
    for (int j = 0; j < 15; ++j) acc = fmaf(ge[j][s], gt[j], acc);
    if (s == t) acc += JITTER;
    sigma_out[((size_t)b * NSEG + s) * NSEG + t] = acc;
  }
}

// ---------------- K4: fused rng + low-rank Cholesky + L@eps + hard ---------
// sigma = jitter*I + G G^T; Schur recurrence on G only (see prior rounds).
// ROW-SPLIT this round: wave w owns rows 64w..64w+63 (ONE slot) and ALL 16
// MC columns — removes the 4x replicated g-recurrence that made the kernel
// per-wave issue-bound (R8-R11: ~330-390 inst/step, instruction cuts moved
// dur, mechanism swaps didn't).  Pivot row crosses waves via DOUBLE-BUFFERED
// LDS (read piv[k&1], write piv[(k+1)&1]) with one __syncthreads per step —
// no same-interval read/write race, and unlike R6/R7's barrier-less pivot
// (unresolved failure) the barrier fences all LDS ordering.
// Every per-(row i, column m) FP op sequence — dot, w-select, acc, g-update,
// norm/rsq/beta (R11 form), logistic — is unchanged: bit-identical output.
__global__ __launch_bounds__(256, 1) void cholmc_kernel(
    const float* __restrict__ Gc, const float* __restrict__ mu,
    uint32_t kg0, uint32_t kg1, uint32_t ku0, uint32_t ku1,
    float* __restrict__ hard) {
  int b = blockIdx.x;
  int tid = threadIdx.x;
  int lane = tid & 63;
  int wave = tid >> 6;
  __shared__ float eps_lds[NSEG * MC];          // 12.25 KB
  __shared__ __align__(16) float piv[2][16];    // double-buffered pivot row

  // prologue: eps = sqrt(2)*erfinv(bits) straight into LDS
  for (int t = tid; t < NSEG * MC; t += 256) {
    uint32_t a0, a1;
    threefry2x32(kg0, kg1, 0u, (uint32_t)(b * NSEG * MC + t), a0, a1);
    float f = bits_to_f01(a0 ^ a1);
    const float lo = -0.99999994f;  // nextafter(-1,0)
    float u = fmaxf(lo, f * (1.0f - lo) + lo);
    eps_lds[t] = 1.4142135623730951f * erfinv_f32(u);
  }

  int i = wave * 64 + lane;  // this thread's row
  float g[15];
#pragma unroll
  for (int j = 0; j < 15; ++j)
    g[j] = (i < NSEG) ? Gc[((size_t)b * 15 + j) * NSEG + i] : 0.0f;
  float acc[16];
#pragma unroll
  for (int m = 0; m < 16; ++m) acc[m] = 0.0f;
  if (tid == 0) {
#pragma unroll
    for (int j = 0; j < 15; ++j) piv[0][j] = g[j];
    piv[0][15] = 0.0f;
  }
  __syncthreads();

  const float sj = 0.031622776601683794f;  // sqrt(jitter)
  for (int k = 0; k < NSEG; ++k) {
    const float* pv = piv[k & 1];
    float4 p0 = *(const float4*)(pv);
    float4 p1 = *(const float4*)(pv + 4);
    float4 p2 = *(const float4*)(pv + 8);
    float4 p3 = *(const float4*)(pv + 12);
    float gk[15] = {p0.x, p0.y, p0.z, p0.w, p1.x, p1.y, p1.z, p1.w,
                    p2.x, p2.y, p2.z, p2.w, p3.x, p3.y, p3.z};
    // R11 tree norm + rsq/rcp (passing numerics, unchanged)
    float t0 = fmaf(gk[0], gk[0], JITTER);
    float t1 = gk[1] * gk[1];   float t2 = gk[2] * gk[2];
    float t3 = gk[3] * gk[3];   float t4 = gk[4] * gk[4];
    float t5 = gk[5] * gk[5];   float t6 = gk[6] * gk[6];
    float t7 = gk[7] * gk[7];   float t8 = gk[8] * gk[8];
    float t9 = gk[9] * gk[9];   float t10 = gk[10] * gk[10];
    float t11 = gk[11] * gk[11]; float t12 = gk[12] * gk[12];
    float t13 = gk[13] * gk[13]; float t14 = gk[14] * gk[14];
    float u0 = t0 + t1, u1 = t2 + t3, u2 = t4 + t5, u3 = t6 + t7;
    float u4 = t8 + t9, u5 = t10 + t11, u6 = t12 + t13;
    float v0 = u0 + u1, v1 = u2 + u3, v2 = u4 + u5, v3 = u6 + t14;
    float jn = (v0 + v1) + (v2 + v3);
    float invd = __builtin_amdgcn_rsqf(jn);
    float dd = jn * invd;
    float beta = (invd * invd) * __builtin_amdgcn_rcpf(fmaf(sj, invd, 1.0f));

    int s0 = k >> 6;
    if (wave >= s0) {  // retired waves just hit the barrier
      const float4* ep = (const float4*)(eps_lds + k * MC);
      float4 e0 = ep[0], e1 = ep[1], e2 = ep[2], e3 = ep[3];
      float ek[16] = {e0.x, e0.y, e0.z, e0.w, e1.x, e1.y, e1.z, e1.w,
                      e2.x, e2.y, e2.z, e2.w, e3.x, e3.y, e3.z, e3.w};
      float dot = 0.0f;
#pragma unroll
      for (int j = 0; j < 15; ++j) dot = fmaf(g[j], gk[j], dot);
      float w;
      if (wave == s0) {
        int owner = k & 63;
        w = (lane > owner) ? dot * invd : ((lane == owner) ? dd : 0.0f);
      } else {
        w = dot * invd;  // i > k always; dead rows (g==+0) give w=+0
      }
#pragma unroll
      for (int m = 0; m < 16; ++m) acc[m] = fmaf(w, ek[m], acc[m]);
      float bd = beta * dot;
#pragma unroll
      for (int j = 0; j < 15; ++j) g[j] = fmaf(-bd, gk[j], g[j]);
      int kn = k + 1;
      if (kn < NSEG && i == kn) {  // single owner lane publishes row k+1
        float* pw = piv[kn & 1];
#pragma unroll
        for (int j = 0; j < 15; ++j) pw[j] = g[j];
      }
    }
    __syncthreads();  // fences publish (buffer kn&1) before next step's read
  }

  // epilogue: hard = (mu + L@eps + logistic) > 0, this thread's row, all m
  if (i < NSEG) {
    float mui = mu[b * NSEG + i];
    float4 outv[4];
    float* op = (float*)outv;
#pragma unroll
    for (int m = 0; m < 16; ++m) {
      uint32_t a0, a1;
      threefry2x32(ku0, ku1, 0u, (uint32_t)(b * NSEG * MC + i * MC + m), a0, a1);
      float f = bits_to_f01(a0 ^ a1);
      const float mn = 1e-6f;
      const float mx = (float)(1.0 - 1e-6);
      float uu = fmaxf(mn, f * (mx - mn) + mn);
      float lg = logf(uu) - log1pf(-uu);
      float z = mui + acc[m] + lg;
      op[m] = (z > 0.0f) ? 1.0f : 0.0f;
    }
    float4* hp = (float4*)(hard + ((size_t)b * NSEG + i) * MC);
#pragma unroll
    for (int q = 0; q < 4; ++q) hp[q] = outv[q];
  }
}

// ---------------- K5: mask gather, one float4 per thread -------------------
__global__ __launch_bounds__(256) void mask_kernel(
    const int* __restrict__ groups, const float* __restrict__ hard,
    float4* __restrict__ out) {
  int f = blockIdx.x * blockDim.x + threadIdx.x;  // float4 index
  if (f >= BATCH * 3 * HW * 4) return;
  int pix = f >> 2;          // (b*3+c)*HW + p
  int q = f & 3;
  int b = pix / (3 * HW);
  int p = pix % HW;
  int g = groups[b * HW + p];
  out[f] = ((const float4*)hard)[(b * NSEG + g) * 4 + q];
}

extern "C" void kernel_launch(void* const* d_in, const int* in_sizes, int n_in,
                              void* d_out, int out_size, void* d_ws, size_t ws_size,
                              hipStream_t stream) {
  const float* x = (const float*)d_in[0];
  const int* groups = (const int*)d_in[1];
  const float* Wc = (const float*)d_in[2];
  const float* bc = (const float*)d_in[3];

  float* out = (float*)d_out;
  float* mask_out = out;                         // 38,535,168
  float* gp_out = out + 38535168;                //      3,136
  float* pp_out = gp_out + 3136;                 //    802,816
  float* sig_out = pp_out + 802816;              //    614,656

  float* ws = (float*)d_ws;
  float* partial = ws;                           // 224*784 = 175,616
  float* mu_ws = ws + 175616;                    //   3,136
  float* Gc    = ws + 178752;                    //  47,040  (tot 903 KB)
  float* hard  = ws;                             // 50,176 — reuses dead partial

  emb_kernel<<<BATCH * EBLK, 256, 0, stream>>>(x, groups, Wc, bc, partial, pp_out);
  stats_kernel<<<BATCH, 256, 0, stream>>>(partial, Wc, bc, mu_ws, gp_out, Gc);
  sigma_kernel<<<BATCH * 7, 256, 0, stream>>>(Gc, sig_out);

  uint32_t kg0, kg1, ku0, ku1;
  threefry2x32(0u, 42u, 0u, 0u, kg0, kg1);
  threefry2x32(0u, 42u, 0u, 1u, ku0, ku1);

  cholmc_kernel<<<BATCH, 256, 0, stream>>>(Gc, mu_ws, kg0, kg1, ku0, ku1, hard);
  mask_kernel<<<(BATCH * 3 * HW * 4 + 255) / 256, 256, 0, stream>>>(
      groups, hard, (float4*)mask_out);
}